// Round 6
// baseline (319.740 us; speedup 1.0000x reference)
//
#include <hip/hip_runtime.h>
#include <hip/hip_bf16.h>

#define B_   2
#define S_   2048
#define D_   2048
#define H_   16
#define KV_  4
#define KQD_ 96
#define VD_  128
#define NQK_ 1920            // H*KQD + KV*KQD = 1536 + 384
#define M_   4096            // B*S

typedef __attribute__((ext_vector_type(8))) short bf16x8;
typedef __attribute__((ext_vector_type(4))) short bf16x4;
typedef __attribute__((ext_vector_type(4))) float f32x4;

__device__ __forceinline__ short f2bf(float f) {
    union { float f; unsigned u; } v; v.f = f;
    unsigned r = (v.u + 0x7fffu + ((v.u >> 16) & 1u)) >> 16;
    return (short)r;
}
__device__ __forceinline__ float bf2f(short s) {
    union { unsigned u; float f; } v; v.u = ((unsigned)(unsigned short)s) << 16;
    return v.f;
}

__device__ __forceinline__ void glds16(const void* g, void* l) {
    __builtin_amdgcn_global_load_lds(
        (__attribute__((address_space(1))) void*)(g),
        (__attribute__((address_space(3))) void*)(l), 16, 0, 0);
}

// DPP-based 16-lane sum (attn epilogue)
template <int CTRL>
__device__ __forceinline__ float dppf(float x) {
    return __int_as_float(__builtin_amdgcn_update_dpp(
        0, __float_as_int(x), CTRL, 0xF, 0xF, true));
}
__device__ __forceinline__ float rsum16(float x) {
    x += dppf<0xB1>(x);     // quad_perm xor1
    x += dppf<0x4E>(x);     // quad_perm xor2
    x += dppf<0x124>(x);    // row_ror:4
    x += dppf<0x128>(x);    // row_ror:8
    return x;
}

// ---------------------------------------------------------------------------
// fp32 -> bf16 for all five inputs in one launch; dests contiguous in ws.
// ---------------------------------------------------------------------------
__global__ __launch_bounds__(256) void cvt_all(
    const float* __restrict__ hs, const float* __restrict__ wq,
    const float* __restrict__ wk, const float* __restrict__ wv,
    const float* __restrict__ wo, short* __restrict__ dst)
{
    int i = blockIdx.x * 256 + threadIdx.x;
    if (i >= 4390912) return;
    const float* s; int off;
    if      (i < 2097152) { s = hs; off = i; }
    else if (i < 2883584) { s = wq; off = i - 2097152; }
    else if (i < 3080192) { s = wk; off = i - 2883584; }
    else if (i < 3342336) { s = wv; off = i - 3080192; }
    else                  { s = wo; off = i - 3342336; }
    float4 v = ((const float4*)s)[off];
    bf16x4 o;
    o.x = f2bf(v.x); o.y = f2bf(v.y); o.z = f2bf(v.z); o.w = f2bf(v.w);
    ((bf16x4*)dst)[i] = o;
}

// ---------------------------------------------------------------------------
// GEMM: C[M x N] = A[M x K] * W[N x K]^T  (bf16 in, fp32 acc)
// 128x64 tile, 256 thr (4 waves = 2M x 2N, wave-tile 64x32, acc[4][2]).
// Granularity proven R5: gemm3 32x38=1216 blocks (95% balance),
// gemm2 32x32=1024 (100%). LDS 48 KB -> 3 blocks/CU.
// T3+T4 pipeline (counted vmcnt, never 0 in main loop), T2 source-side
// XOR swizzle (conflicts == 0 measured), T1 bijective XCD swizzle.
// OUT==2: fp32 row-major.  OUT==3: fused QKV (n0<NQK_ row-major bf16;
// n0>=NQK_ transposed V^T; NQK_=1920=30*64 -> 64-col tiles split cleanly).
// ---------------------------------------------------------------------------
template <int OUT>
__global__ __launch_bounds__(256) void gemm_bt(
    const short* __restrict__ A, const short* __restrict__ W,
    void* __restrict__ Cv, void* __restrict__ Cv2, int M, int N, int K)
{
    __shared__ short As[2][128 * 64];   // 32 KB
    __shared__ short Bs[2][64 * 64];    // 16 KB

    const int tid  = threadIdx.x;
    const int wv   = tid >> 6;
    const int lane = tid & 63;
    const int wm   = wv >> 1;            // 0..1: 64-row band
    const int wn   = wv & 1;             // 0..1: 32-col band
    const int l16  = lane & 15;
    const int qd   = lane >> 4;

    // bijective chunked XCD swizzle (m204)
    const int nbx = gridDim.x, nby = gridDim.y;
    const int nwg = nbx * nby;
    const int p   = blockIdx.x + blockIdx.y * nbx;    // hw dispatch order
    const int q8  = nwg >> 3, r8 = nwg & 7;
    const int xcd = p & 7, slot = p >> 3;
    const int logical = (xcd < r8) ? xcd * (q8 + 1) + slot
                                   : r8 * (q8 + 1) + (xcd - r8) * q8 + slot;
    const int m0 = (logical / nby) * 128;
    const int n0 = (logical % nby) * 64;

    auto stage = [&](int t, int buf) {
        const int k0 = t * 64;
        // A: 128 rows x 8 granules = 1024, 4 rounds of 256
#pragma unroll
        for (int r = 0; r < 4; ++r) {
            int flat = r * 256 + tid;
            int row = flat >> 3, gd = flat & 7;
            int gs = gd ^ (row & 7);
            glds16(A + (long)(m0 + row) * K + k0 + gs * 8,
                   As[buf] + (r * 256 + wv * 64) * 8);
        }
        // B: 64 rows x 8 granules = 512, 2 rounds
#pragma unroll
        for (int r = 0; r < 2; ++r) {
            int flat = r * 256 + tid;
            int row = flat >> 3, gd = flat & 7;
            int gs = gd ^ (row & 7);
            glds16(W + (long)(n0 + row) * K + k0 + gs * 8,
                   Bs[buf] + (r * 256 + wv * 64) * 8);
        }
    };

    stage(0, 0);
    stage(1, 1);          // 12 glds/thread outstanding

    f32x4 acc[4][2] = {};
    const int NT = K >> 6;

    for (int t = 0; t < NT; ++t) {
        const int buf = t & 1;
        if (t + 1 < NT) asm volatile("s_waitcnt vmcnt(6)" ::: "memory");
        else            asm volatile("s_waitcnt vmcnt(0)" ::: "memory");
        __builtin_amdgcn_s_barrier();
        __builtin_amdgcn_sched_barrier(0);   // no ds_read hoists above barrier

#pragma unroll
        for (int kh = 0; kh < 2; ++kh) {
            bf16x8 af[4], bfr[2];
#pragma unroll
            for (int i = 0; i < 4; ++i) {
                int ar = wm * 64 + i * 16 + l16;
                af[i] = *(const bf16x8*)(As[buf] + ar * 64
                            + (((kh * 4 + qd) ^ (ar & 7)) * 8));
            }
#pragma unroll
            for (int j = 0; j < 2; ++j) {
                int br = wn * 32 + j * 16 + l16;
                bfr[j] = *(const bf16x8*)(Bs[buf] + br * 64
                            + (((kh * 4 + qd) ^ (br & 7)) * 8));
            }
            __builtin_amdgcn_s_setprio(1);
#pragma unroll
            for (int i = 0; i < 4; ++i)
#pragma unroll
                for (int j = 0; j < 2; ++j)
                    acc[i][j] = __builtin_amdgcn_mfma_f32_16x16x32_bf16(
                        af[i], bfr[j], acc[i][j], 0, 0, 0);
            __builtin_amdgcn_s_setprio(0);
        }

        __builtin_amdgcn_sched_barrier(0);
        __builtin_amdgcn_s_barrier();        // all reads of buf done
        if (t + 2 < NT) stage(t + 2, buf);   // refill; stays in flight
    }

    if (OUT == 2) {
        float* C = (float*)Cv;
#pragma unroll
        for (int i = 0; i < 4; ++i) {
            int row0 = m0 + wm * 64 + i * 16 + qd * 4;
#pragma unroll
            for (int j = 0; j < 2; ++j) {
                int col = n0 + wn * 32 + j * 16 + l16;
#pragma unroll
                for (int r = 0; r < 4; ++r)
                    C[(long)(row0 + r) * N + col] = acc[i][j][r];
            }
        }
    } else {  // OUT == 3
        if (n0 < NQK_) {
            short* C = (short*)Cv;
#pragma unroll
            for (int i = 0; i < 4; ++i) {
                int row0 = m0 + wm * 64 + i * 16 + qd * 4;
#pragma unroll
                for (int j = 0; j < 2; ++j) {
                    int col = n0 + wn * 32 + j * 16 + l16;
#pragma unroll
                    for (int r = 0; r < 4; ++r)
                        C[(long)(row0 + r) * NQK_ + col] = f2bf(acc[i][j][r]);
                }
            }
        } else {
            short* C = (short*)Cv2;
#pragma unroll
            for (int i = 0; i < 4; ++i) {
                int row0 = m0 + wm * 64 + i * 16 + qd * 4;
#pragma unroll
                for (int j = 0; j < 2; ++j) {
                    int vcol = n0 - NQK_ + wn * 32 + j * 16 + l16;
                    bf16x4 pk;
                    pk.x = f2bf(acc[i][j][0]); pk.y = f2bf(acc[i][j][1]);
                    pk.z = f2bf(acc[i][j][2]); pk.w = f2bf(acc[i][j][3]);
                    *(bf16x4*)(C + (long)vcol * M_ + row0) = pk;  // V^T
                }
            }
        }
    }
}

// ---------------------------------------------------------------------------
// RMSNorm + RoPE, in place on fused qk buffer (row stride NQK_).
// Q additionally pre-scaled by (1/sqrt(96))*log2(e) -> exp2-domain scores.
// ---------------------------------------------------------------------------
__global__ __launch_bounds__(256) void rms_rope(
    short* __restrict__ qk, const float* __restrict__ qw,
    const float* __restrict__ kw, const int* __restrict__ pos_ids)
{
    int wid  = (int)((blockIdx.x * 256 + threadIdx.x) >> 6);
    int lane = threadIdx.x & 63;

    short* v; const float* w; int row; float qs;
    if (wid < 65536) {                       // q: 4096 rows x 16 heads
        row = wid >> 4;
        v = qk + (long)row * NQK_ + (wid & 15) * 96;
        w = qw;
        qs = 0.14724444f;                    // (1/sqrt(96)) * log2(e)
    } else {                                 // k: 4096 rows x 4 heads
        int t = wid - 65536;
        row = t >> 2;
        v = qk + (long)row * NQK_ + 1536 + (t & 3) * 96;
        w = kw;
        qs = 1.0f;
    }

    float x0 = 0.f, x1 = 0.f;
    if (lane < 48) { x0 = bf2f(v[lane]); x1 = bf2f(v[lane + 48]); }
    float ss = x0 * x0 + x1 * x1;
#pragma unroll
    for (int off = 1; off < 64; off <<= 1) ss += __shfl_xor(ss, off, 64);
    float rr = rsqrtf(ss * (1.0f / 96.0f) + 1e-6f);

    if (lane < 48) {
        int pos = pos_ids[row];
        float y0 = (x0 * rr) * w[lane] * qs;
        float y1 = (x1 * rr) * w[lane + 48] * qs;
        float inv = exp2f(-(float)lane * (13.287712379549449f / 48.0f));
        float fr  = (float)pos * inv;
        float c, s;
        sincosf(fr, &s, &c);
        v[lane]      = f2bf(y0 * c - y1 * s);
        v[lane + 48] = f2bf(y1 * c + y0 * s);
    }
}

// ---------------------------------------------------------------------------
// Flash attention (causal, GQA 4:1). R0's PROVEN inner loop (identical
// fragments, Ps layout, softmax, epilogue) with ONLY the occupancy geometry
// changed:
//  - ONE 64-row q-tile per block, grid (32 bh, 32 qi); balanced qt map:
//    CU c receives blocks {c, c+256, c+512, c+768} = qt quads summing to 62
//    -> equal work per CU.
//  - SINGLE-buffered Ks/Vs + register prefetch of kt+1 (loads issued before
//    compute, in flight through QK^T/softmax/PV; storeKV between two
//    barriers). LDS = 13 (Ks) + 18 (Vs) + 9 (Ps) = 40960 B exactly
//    -> 4 blocks/CU (163840 B = full pool), 16 waves/CU = 4 waves/SIMD
//    (vs R0's 2/SIMD -- attn is latency-exposed, every pipe <40% busy).
//  - plain launch_bounds(256): natural 116 VGPR < 128 already allows
//    4 waves/SIMD. R1's (256,4) forced a 64-VGPR split + 66 MB spills; R3's
//    512-thr kv-split added barriers. The geometry was right both times.
// exp2-domain STATIC-MAX softmax: |q|=|k|=sqrt(96), RoPE norm-preserving,
// score*log2e <= 14.14 < 14.5; p = exp2(s - 14.5), no running max.
// qk: fused (M x NQK_)  vt: (KV*VD x M)  out: (B,S,H*128) bf16
// ---------------------------------------------------------------------------
__global__ __launch_bounds__(256) void attn(
    const short* __restrict__ qk, const short* __restrict__ vt,
    short* __restrict__ out)
{
    __shared__ short Ks[64 * 104];       // 13.0 KB
    __shared__ short Vs[128 * 72];       // 18.0 KB
    __shared__ short Ps[4][16 * 72];     //  9.0 KB   -> 40960 B total

    const int tid  = threadIdx.x;
    const int lane = tid & 63;
    const int wv   = tid >> 6;
    const int bh   = blockIdx.x;          // 0..31  (fastest dispatch dim)
    const int qi   = blockIdx.y;          // 0..31
    const int b    = bh >> 4, h = bh & 15;
    const int kvh  = h >> 2;
    const int l16  = lane & 15;
    const int qd   = lane >> 4;
    const long bS  = (long)b * S_;

    // balanced qt permutation: qt(qi)+qt(qi+8)+qt(qi+16)+qt(qi+24) == 62
    int qt;
    if      (qi <  8) qt = 31 - 2 * qi;
    else if (qi < 16) qt = 46 - 2 * qi;
    else if (qi < 24) qt = 2 * qi - 32;
    else              qt = 2 * qi - 47;
    const int q0 = qt * 64;

    const short* kbase = qk + bS * NQK_ + 1536 + kvh * 96;
    const short* vbase = vt + (long)kvh * 128 * (B_ * S_) + bS;

    auto loadK = [&](int k0, bf16x8* kr) {
#pragma unroll
        for (int r = 0; r < 3; ++r) {
            int flat = r * 256 + tid;
            int row = flat / 12, ch = flat % 12;
            kr[r] = *(const bf16x8*)(kbase + (long)(k0 + row) * NQK_ + ch * 8);
        }
    };
    auto loadV = [&](int k0, bf16x8* vr) {
#pragma unroll
        for (int r = 0; r < 4; ++r) {
            int flat = r * 256 + tid;
            int row = flat >> 3, ch = flat & 7;
            vr[r] = *(const bf16x8*)(vbase + (long)row * (B_ * S_) + k0 + ch * 8);
        }
    };
    auto storeKV = [&](bf16x8* kr, bf16x8* vr) {
#pragma unroll
        for (int r = 0; r < 3; ++r) {
            int flat = r * 256 + tid;
            int row = flat / 12, ch = flat % 12;
            *(bf16x8*)(Ks + row * 104 + ch * 8) = kr[r];
        }
#pragma unroll
        for (int r = 0; r < 4; ++r) {
            int flat = r * 256 + tid;
            int row = flat >> 3, ch = flat & 7;
            *(bf16x8*)(Vs + row * 72 + ch * 8) = vr[r];
        }
    };

    // Q fragments (registers for the whole block's lifetime)
    bf16x8 qf[3];
    {
        int s = q0 + wv * 16 + l16;
        const short* qp = qk + (bS + s) * NQK_ + h * 96 + qd * 8;
        qf[0] = *(const bf16x8*)(qp);
        qf[1] = *(const bf16x8*)(qp + 32);
        qf[2] = *(const bf16x8*)(qp + 64);
    }

    float rs[4] = {0.f, 0.f, 0.f, 0.f};   // un-reduced l accumulators
    f32x4 o[8] = {};

    {
        bf16x8 kr[3], vr[4];
        loadK(0, kr); loadV(0, vr);
        storeKV(kr, vr);
        __syncthreads();
    }

    for (int kt = 0; kt <= qt; ++kt) {
        const bool more = (kt < qt);
        bf16x8 kn[3], vn[4];
        if (more) { loadK((kt + 1) * 64, kn); loadV((kt + 1) * 64, vn); }

        // S (exp2 domain, statically bounded by 14.14): Q K^T
        f32x4 sa[4];
#pragma unroll
        for (int j = 0; j < 4; ++j) {
            f32x4 a = {};
#pragma unroll
            for (int f = 0; f < 3; ++f) {
                bf16x8 kf = *(const bf16x8*)(Ks + (j * 16 + l16) * 104 + f * 32 + qd * 8);
                a = __builtin_amdgcn_mfma_f32_16x16x32_bf16(qf[f], kf, a, 0, 0, 0);
            }
            sa[j] = a;
        }
        if (kt == qt) {   // causal mask, diagonal tile only
            int qrow = wv * 16 + qd * 4;
#pragma unroll
            for (int j = 0; j < 4; ++j) {
                int kj = j * 16 + l16;
#pragma unroll
                for (int r = 0; r < 4; ++r)
                    if (kj > qrow + r) sa[j][r] = -30000.0f;
            }
        }

        // static-max softmax: p = exp2(s - M); no max tracking, no rescale
#pragma unroll
        for (int j = 0; j < 4; ++j)
#pragma unroll
            for (int r = 0; r < 4; ++r) {
                float p = exp2f(sa[j][r] - 14.5f);
                rs[r] += p;
                Ps[wv][(qd * 4 + r) * 72 + j * 16 + l16] = f2bf(p);
            }

        // PV
        bf16x8 pf[2];
#pragma unroll
        for (int c = 0; c < 2; ++c)
            pf[c] = *(const bf16x8*)(&Ps[wv][l16 * 72 + c * 32 + qd * 8]);
#pragma unroll
        for (int t = 0; t < 8; ++t)
#pragma unroll
            for (int c = 0; c < 2; ++c) {
                bf16x8 vf = *(const bf16x8*)(Vs + (t * 16 + l16) * 72 + c * 32 + qd * 8);
                o[t] = __builtin_amdgcn_mfma_f32_16x16x32_bf16(pf[c], vf, o[t], 0, 0, 0);
            }

        if (more) {
            __syncthreads();          // all waves done reading Ks/Vs
            storeKV(kn, vn);
            __syncthreads();          // kt+1 tile visible
        }
    }

    // epilogue: reduce l once, O / l
    float inv[4];
#pragma unroll
    for (int r = 0; r < 4; ++r) inv[r] = 1.0f / rsum16(rs[r]);
#pragma unroll
    for (int t = 0; t < 8; ++t)
#pragma unroll
        for (int r = 0; r < 4; ++r) {
            int s = q0 + wv * 16 + qd * 4 + r;
            out[((bS + s) * H_ + h) * 128 + t * 16 + l16] =
                f2bf(o[t][r] * inv[r]);
        }
}

// ---------------------------------------------------------------------------
extern "C" void kernel_launch(void* const* d_in, const int* in_sizes, int n_in,
                              void* d_out, int out_size, void* d_ws, size_t ws_size,
                              hipStream_t stream)
{
    const float* hs  = (const float*)d_in[0];
    const int*   pos = (const int*)d_in[1];
    const float* Wq  = (const float*)d_in[2];
    const float* Wk  = (const float*)d_in[3];
    const float* Wv  = (const float*)d_in[4];
    const float* Wo  = (const float*)d_in[5];
    const float* qnw = (const float*)d_in[6];
    const float* knw = (const float*)d_in[7];
    float* out = (float*)d_out;
    short* ws  = (short*)d_ws;

    short* hsb   = ws;                         // 4096 x 2048
    short* Wqkvb = hsb + (long)M_ * D_;        // 2432 x 2048 (Wq|Wk|Wv rows)
    short* Wob   = Wqkvb + (long)2432 * D_;    // 2048 x 2048
    short* qk_ws = Wob + (long)D_ * 2048;      // 4096 x 1920 (q | k fused)
    short* vt_ws = qk_ws + (long)M_ * NQK_;    // 512 x 4096  (V^T)
    short* ao_ws = vt_ws + (long)512 * M_;     // 4096 x 2048

    cvt_all<<<17152, 256, 0, stream>>>(hs, Wq, Wk, Wv, Wo, ws);

    gemm_bt<3><<<dim3(32, 38), 256, 0, stream>>>(
        hsb, Wqkvb, qk_ws, vt_ws, M_, 2432, D_);

    rms_rope<<<(65536 + 16384) / 4, 256, 0, stream>>>(qk_ws, qnw, knw, pos);

    attn<<<dim3(32, 32), 256, 0, stream>>>(qk_ws, vt_ws, ao_ws);

    gemm_bt<2><<<dim3(32, 32), 256, 0, stream>>>(
        ao_ws, Wob, (void*)out, nullptr, M_, D_, H_ * VD_);
}

// Round 7
// 311.753 us; speedup vs baseline: 1.0256x; 1.0256x over previous
//
#include <hip/hip_runtime.h>
#include <hip/hip_bf16.h>

#define B_   2
#define S_   2048
#define D_   2048
#define H_   16
#define KV_  4
#define KQD_ 96
#define VD_  128
#define NQK_ 1920            // H*KQD + KV*KQD = 1536 + 384
#define M_   4096            // B*S

typedef __attribute__((ext_vector_type(8))) short bf16x8;
typedef __attribute__((ext_vector_type(4))) short bf16x4;
typedef __attribute__((ext_vector_type(4))) float f32x4;

__device__ __forceinline__ short f2bf(float f) {
    union { float f; unsigned u; } v; v.f = f;
    unsigned r = (v.u + 0x7fffu + ((v.u >> 16) & 1u)) >> 16;
    return (short)r;
}
__device__ __forceinline__ float bf2f(short s) {
    union { unsigned u; float f; } v; v.u = ((unsigned)(unsigned short)s) << 16;
    return v.f;
}

__device__ __forceinline__ void glds16(const void* g, void* l) {
    __builtin_amdgcn_global_load_lds(
        (__attribute__((address_space(1))) void*)(g),
        (__attribute__((address_space(3))) void*)(l), 16, 0, 0);
}

// DPP-based 16-lane sum (attn epilogue)
template <int CTRL>
__device__ __forceinline__ float dppf(float x) {
    return __int_as_float(__builtin_amdgcn_update_dpp(
        0, __float_as_int(x), CTRL, 0xF, 0xF, true));
}
__device__ __forceinline__ float rsum16(float x) {
    x += dppf<0xB1>(x);     // quad_perm xor1
    x += dppf<0x4E>(x);     // quad_perm xor2
    x += dppf<0x124>(x);    // row_ror:4
    x += dppf<0x128>(x);    // row_ror:8
    return x;
}

// ---------------------------------------------------------------------------
// fp32 -> bf16 for all five inputs in one launch; dests contiguous in ws.
// ---------------------------------------------------------------------------
__global__ __launch_bounds__(256) void cvt_all(
    const float* __restrict__ hs, const float* __restrict__ wq,
    const float* __restrict__ wk, const float* __restrict__ wv,
    const float* __restrict__ wo, short* __restrict__ dst)
{
    int i = blockIdx.x * 256 + threadIdx.x;
    if (i >= 4390912) return;
    const float* s; int off;
    if      (i < 2097152) { s = hs; off = i; }
    else if (i < 2883584) { s = wq; off = i - 2097152; }
    else if (i < 3080192) { s = wk; off = i - 2883584; }
    else if (i < 3342336) { s = wv; off = i - 3080192; }
    else                  { s = wo; off = i - 3342336; }
    float4 v = ((const float4*)s)[off];
    bf16x4 o;
    o.x = f2bf(v.x); o.y = f2bf(v.y); o.z = f2bf(v.z); o.w = f2bf(v.w);
    ((bf16x4*)dst)[i] = o;
}

// ---------------------------------------------------------------------------
// GEMM: C[M x N] = A[M x K] * W[N x K]^T  (bf16 in, fp32 acc)
// 128x64 tile, 256 thr (4 waves = 2M x 2N, wave-tile 64x32, acc[4][2]).
// Granularity proven R5: gemm3 32x38=1216 blocks (95% balance),
// gemm2 32x32=1024 (100%). LDS 48 KB -> 3 blocks/CU.
// T3+T4 pipeline (counted vmcnt, never 0 in main loop), T2 source-side
// XOR swizzle (conflicts == 0 measured), T1 bijective XCD swizzle.
// OUT==2: fp32 row-major.  OUT==3: fused QKV (n0<NQK_ row-major bf16;
// n0>=NQK_ transposed V^T; NQK_=1920=30*64 -> 64-col tiles split cleanly).
// ---------------------------------------------------------------------------
template <int OUT>
__global__ __launch_bounds__(256) void gemm_bt(
    const short* __restrict__ A, const short* __restrict__ W,
    void* __restrict__ Cv, void* __restrict__ Cv2, int M, int N, int K)
{
    __shared__ short As[2][128 * 64];   // 32 KB
    __shared__ short Bs[2][64 * 64];    // 16 KB

    const int tid  = threadIdx.x;
    const int wv   = tid >> 6;
    const int lane = tid & 63;
    const int wm   = wv >> 1;            // 0..1: 64-row band
    const int wn   = wv & 1;             // 0..1: 32-col band
    const int l16  = lane & 15;
    const int qd   = lane >> 4;

    // bijective chunked XCD swizzle (m204)
    const int nbx = gridDim.x, nby = gridDim.y;
    const int nwg = nbx * nby;
    const int p   = blockIdx.x + blockIdx.y * nbx;    // hw dispatch order
    const int q8  = nwg >> 3, r8 = nwg & 7;
    const int xcd = p & 7, slot = p >> 3;
    const int logical = (xcd < r8) ? xcd * (q8 + 1) + slot
                                   : r8 * (q8 + 1) + (xcd - r8) * q8 + slot;
    const int m0 = (logical / nby) * 128;
    const int n0 = (logical % nby) * 64;

    auto stage = [&](int t, int buf) {
        const int k0 = t * 64;
        // A: 128 rows x 8 granules = 1024, 4 rounds of 256
#pragma unroll
        for (int r = 0; r < 4; ++r) {
            int flat = r * 256 + tid;
            int row = flat >> 3, gd = flat & 7;
            int gs = gd ^ (row & 7);
            glds16(A + (long)(m0 + row) * K + k0 + gs * 8,
                   As[buf] + (r * 256 + wv * 64) * 8);
        }
        // B: 64 rows x 8 granules = 512, 2 rounds
#pragma unroll
        for (int r = 0; r < 2; ++r) {
            int flat = r * 256 + tid;
            int row = flat >> 3, gd = flat & 7;
            int gs = gd ^ (row & 7);
            glds16(W + (long)(n0 + row) * K + k0 + gs * 8,
                   Bs[buf] + (r * 256 + wv * 64) * 8);
        }
    };

    stage(0, 0);
    stage(1, 1);          // 12 glds/thread outstanding

    f32x4 acc[4][2] = {};
    const int NT = K >> 6;

    for (int t = 0; t < NT; ++t) {
        const int buf = t & 1;
        if (t + 1 < NT) asm volatile("s_waitcnt vmcnt(6)" ::: "memory");
        else            asm volatile("s_waitcnt vmcnt(0)" ::: "memory");
        __builtin_amdgcn_s_barrier();
        __builtin_amdgcn_sched_barrier(0);   // no ds_read hoists above barrier

#pragma unroll
        for (int kh = 0; kh < 2; ++kh) {
            bf16x8 af[4], bfr[2];
#pragma unroll
            for (int i = 0; i < 4; ++i) {
                int ar = wm * 64 + i * 16 + l16;
                af[i] = *(const bf16x8*)(As[buf] + ar * 64
                            + (((kh * 4 + qd) ^ (ar & 7)) * 8));
            }
#pragma unroll
            for (int j = 0; j < 2; ++j) {
                int br = wn * 32 + j * 16 + l16;
                bfr[j] = *(const bf16x8*)(Bs[buf] + br * 64
                            + (((kh * 4 + qd) ^ (br & 7)) * 8));
            }
            __builtin_amdgcn_s_setprio(1);
#pragma unroll
            for (int i = 0; i < 4; ++i)
#pragma unroll
                for (int j = 0; j < 2; ++j)
                    acc[i][j] = __builtin_amdgcn_mfma_f32_16x16x32_bf16(
                        af[i], bfr[j], acc[i][j], 0, 0, 0);
            __builtin_amdgcn_s_setprio(0);
        }

        __builtin_amdgcn_sched_barrier(0);
        __builtin_amdgcn_s_barrier();        // all reads of buf done
        if (t + 2 < NT) stage(t + 2, buf);   // refill; stays in flight
    }

    if (OUT == 2) {
        float* C = (float*)Cv;
#pragma unroll
        for (int i = 0; i < 4; ++i) {
            int row0 = m0 + wm * 64 + i * 16 + qd * 4;
#pragma unroll
            for (int j = 0; j < 2; ++j) {
                int col = n0 + wn * 32 + j * 16 + l16;
#pragma unroll
                for (int r = 0; r < 4; ++r)
                    C[(long)(row0 + r) * N + col] = acc[i][j][r];
            }
        }
    } else {  // OUT == 3
        if (n0 < NQK_) {
            short* C = (short*)Cv;
#pragma unroll
            for (int i = 0; i < 4; ++i) {
                int row0 = m0 + wm * 64 + i * 16 + qd * 4;
#pragma unroll
                for (int j = 0; j < 2; ++j) {
                    int col = n0 + wn * 32 + j * 16 + l16;
#pragma unroll
                    for (int r = 0; r < 4; ++r)
                        C[(long)(row0 + r) * NQK_ + col] = f2bf(acc[i][j][r]);
                }
            }
        } else {
            short* C = (short*)Cv2;
#pragma unroll
            for (int i = 0; i < 4; ++i) {
                int row0 = m0 + wm * 64 + i * 16 + qd * 4;
#pragma unroll
                for (int j = 0; j < 2; ++j) {
                    int vcol = n0 - NQK_ + wn * 32 + j * 16 + l16;
                    bf16x4 pk;
                    pk.x = f2bf(acc[i][j][0]); pk.y = f2bf(acc[i][j][1]);
                    pk.z = f2bf(acc[i][j][2]); pk.w = f2bf(acc[i][j][3]);
                    *(bf16x4*)(C + (long)vcol * M_ + row0) = pk;  // V^T
                }
            }
        }
    }
}

// ---------------------------------------------------------------------------
// RMSNorm + RoPE, in place on fused qk buffer (row stride NQK_).
// Q additionally pre-scaled by (1/sqrt(96))*log2(e) -> exp2-domain scores.
// ---------------------------------------------------------------------------
__global__ __launch_bounds__(256) void rms_rope(
    short* __restrict__ qk, const float* __restrict__ qw,
    const float* __restrict__ kw, const int* __restrict__ pos_ids)
{
    int wid  = (int)((blockIdx.x * 256 + threadIdx.x) >> 6);
    int lane = threadIdx.x & 63;

    short* v; const float* w; int row; float qs;
    if (wid < 65536) {                       // q: 4096 rows x 16 heads
        row = wid >> 4;
        v = qk + (long)row * NQK_ + (wid & 15) * 96;
        w = qw;
        qs = 0.14724444f;                    // (1/sqrt(96)) * log2(e)
    } else {                                 // k: 4096 rows x 4 heads
        int t = wid - 65536;
        row = t >> 2;
        v = qk + (long)row * NQK_ + 1536 + (t & 3) * 96;
        w = kw;
        qs = 1.0f;
    }

    float x0 = 0.f, x1 = 0.f;
    if (lane < 48) { x0 = bf2f(v[lane]); x1 = bf2f(v[lane + 48]); }
    float ss = x0 * x0 + x1 * x1;
#pragma unroll
    for (int off = 1; off < 64; off <<= 1) ss += __shfl_xor(ss, off, 64);
    float rr = rsqrtf(ss * (1.0f / 96.0f) + 1e-6f);

    if (lane < 48) {
        int pos = pos_ids[row];
        float y0 = (x0 * rr) * w[lane] * qs;
        float y1 = (x1 * rr) * w[lane + 48] * qs;
        float inv = exp2f(-(float)lane * (13.287712379549449f / 48.0f));
        float fr  = (float)pos * inv;
        float c, s;
        sincosf(fr, &s, &c);
        v[lane]      = f2bf(y0 * c - y1 * s);
        v[lane + 48] = f2bf(y1 * c + y0 * s);
    }
}

// ---------------------------------------------------------------------------
// Flash attention (causal, GQA 4:1). 512-thread / 8-wave blocks:
// 4 q-subwaves (wq: 16 rows each) x 2 kv-halves (we: 32 cols each).
// Triangle-paired grid (16 pair, 32 bh): every block = exactly 33 units
// serial (2 passes) -> UNIFORM durations (R6 lesson: with all blocks
// resident at t=0, only per-block uniformity matters, not per-CU sums).
// Waves/CU doubles vs R0 (16 vs 8) at identical LDS traffic per unit of
// work: per wave-unit 6 K-frag + 8 V-frag + 1 P-frag reads + 8 b16 writes,
// 14 MFMA (R0: 12+16+2+16, 24 MFMA for 2x the work).
// LDS = 26624 (Ks dbuf, stride 104, glds-staged with 13-granule rows:
// 12 data + 1 pad-from-dummy, R3-proven; b128 frag reads floor-optimal)
// + 32768 (Vs dbuf, stride 64, glds source-pre-swizzled g^(row&7),
// R2-proven) + 9216 (Ps stride 36: qd-groups on disjoint bank octets,
// fixes stride-72's qd 0/2,1/3 write collisions) = 68608 B -> 2 blocks/CU
// WITH MARGIN. (R3 failed at 2x79872=159744: the usable pool is slightly
// under 163840 -- the hidden occupancy killer of R3/R6.)
// One barrier per unit: sync (glds(kt) landed + buf^1 reads of kt-1 done)
// -> stage(kt+1, buf^1) -> compute(buf). Epilogue: kv-halves combine via
// Ks/Vs-as-scratch (o-dump fits Vs exactly: 256 lanes x 128 B = 32 KB).
// exp2-domain STATIC-MAX softmax: |q|=|k|=sqrt(96), RoPE norm-preserving,
// score*log2e <= 14.14 < 14.5; p = exp2(s - 14.5), no running max.
// qk: fused (M x NQK_)  vt: (KV*VD x M)  out: (B,S,H*128) bf16
// ---------------------------------------------------------------------------
__global__ __launch_bounds__(512) void attn(
    const short* __restrict__ qk, const short* __restrict__ vt,
    short* __restrict__ out)
{
    __shared__ short Ks[2][64 * 104];    // 26624 B
    __shared__ short Vs[2][128 * 64];    // 32768 B
    __shared__ short Ps[8][16 * 36];     //  9216 B  -> 68608 B total

    const int tid  = threadIdx.x;
    const int lane = tid & 63;
    const int wv   = tid >> 6;           // 0..7
    const int wq   = wv & 3;             // q sub-tile (16 rows)
    const int we   = wv >> 2;            // kv half (32 cols)
    const int pair = blockIdx.x;         // 0..15
    const int bh   = blockIdx.y;         // 0..31
    const int b    = bh >> 4, h = bh & 15;
    const int kvh  = h >> 2;
    const int l16  = lane & 15;
    const int qd   = lane >> 4;
    const long bS  = (long)b * S_;

    const short* kbase = qk + bS * NQK_ + 1536 + kvh * 96;
    const short* vbase = vt + (long)kvh * 128 * (B_ * S_) + bS;

    // glds staging. K: 64 rows x 13 granules (12 data + 1 pad) = 832 =
    // 512 + 320; LDS dest linear (13 x 16B = 208 B = row stride exactly).
    // V: 128 rows x 8 granules = 1024 = 2 x 512; source granule
    // pre-swizzled g ^ (row & 7), LDS dest linear.
    auto stage = [&](int k0, int buf) {
        {
            int flat = tid;
            int row = flat / 13, ch = flat % 13;
            const short* src = (ch < 12)
                ? (kbase + (long)(k0 + row) * NQK_ + ch * 8) : kbase;
            glds16(src, Ks[buf] + (wv * 64) * 8);
        }
        if (tid < 320) {
            int flat = 512 + tid;
            int row = flat / 13, ch = flat % 13;
            const short* src = (ch < 12)
                ? (kbase + (long)(k0 + row) * NQK_ + ch * 8) : kbase;
            glds16(src, Ks[buf] + (512 + wv * 64) * 8);
        }
#pragma unroll
        for (int r = 0; r < 2; ++r) {
            int flat = r * 512 + tid;
            int row = flat >> 3;
            int g   = (flat & 7) ^ (row & 7);
            glds16(vbase + (long)row * (B_ * S_) + k0 + g * 8,
                   Vs[buf] + (r * 512 + wv * 64) * 8);
        }
    };

#pragma unroll 1
    for (int pass = 0; pass < 2; ++pass) {
        const int qt = pass == 0 ? (31 - pair) : pair;
        const int q0 = qt * 64;

        bf16x8 qf[3];
        {
            int s = q0 + wq * 16 + l16;
            const short* qp = qk + (bS + s) * NQK_ + h * 96 + qd * 8;
            qf[0] = *(const bf16x8*)(qp);
            qf[1] = *(const bf16x8*)(qp + 32);
            qf[2] = *(const bf16x8*)(qp + 64);
        }

        float rs[4] = {0.f, 0.f, 0.f, 0.f};   // partial l (this kv half)
        f32x4 o[8] = {};                       // partial O (this kv half)

        stage(0, 0);   // prologue (pass 1: issued after epilogue's final sync)

        for (int kt = 0; kt <= qt; ++kt) {
            const int buf = kt & 1;
            __syncthreads();   // glds(kt) landed; buf^1 reads of kt-1 done
            if (kt < qt) stage((kt + 1) * 64, buf ^ 1);  // in flight

            // S = Q K^T on this wave's kv half (exp2 domain)
            f32x4 sa[2] = {};
#pragma unroll
            for (int j = 0; j < 2; ++j)
#pragma unroll
                for (int f = 0; f < 3; ++f) {
                    bf16x8 kf = *(const bf16x8*)(Ks[buf]
                        + (we * 32 + j * 16 + l16) * 104 + f * 32 + qd * 8);
                    sa[j] = __builtin_amdgcn_mfma_f32_16x16x32_bf16(
                        qf[f], kf, sa[j], 0, 0, 0);
                }

            if (kt == qt) {   // causal mask, diagonal tile only
                int qloc = wq * 16 + qd * 4;
#pragma unroll
                for (int j = 0; j < 2; ++j) {
                    int kloc = we * 32 + j * 16 + l16;
#pragma unroll
                    for (int r = 0; r < 4; ++r)
                        if (kloc > qloc + r) sa[j][r] = -30000.0f;
                }
            }

            // static-max softmax: p = exp2(s - M)
#pragma unroll
            for (int j = 0; j < 2; ++j)
#pragma unroll
                for (int r = 0; r < 4; ++r) {
                    float p = exp2f(sa[j][r] - 14.5f);
                    rs[r] += p;
                    Ps[wv][(qd * 4 + r) * 36 + j * 16 + l16] = f2bf(p);
                }

            // PV (K=32 = this wave's kv half; single P fragment)
            bf16x8 pf = *(const bf16x8*)(&Ps[wv][l16 * 36 + qd * 8]);
#pragma unroll
            for (int t = 0; t < 8; ++t) {
                bf16x8 vf = *(const bf16x8*)(Vs[buf] + (t * 16 + l16) * 64
                            + (((we * 4 + qd) ^ (l16 & 7)) * 8));
                o[t] = __builtin_amdgcn_mfma_f32_16x16x32_bf16(
                    pf, vf, o[t], 0, 0, 0);
            }
        }

        // ---- epilogue: combine kv halves through Ks/Vs scratch ----
        __syncthreads();              // all PV reads of Ks/Vs done
        f32x4* ov = (f32x4*)&Vs[0][0];    // 8192 floats = 32 KB (exact fit)
        f32x4* rv = (f32x4*)&Ks[0][0];    // 1024 f32x4 needed: 4 KB
        if (we == 1) {
#pragma unroll
            for (int t = 0; t < 8; ++t)
                ov[(wq * 64 + lane) * 8 + t] = o[t];
            f32x4 rt = { rs[0], rs[1], rs[2], rs[3] };
            rv[wq * 64 + lane] = rt;
        }
        __syncthreads();
        if (we == 0) {
#pragma unroll
            for (int t = 0; t < 8; ++t) {
                f32x4 t2 = ov[(wq * 64 + lane) * 8 + t];
                o[t][0] += t2[0]; o[t][1] += t2[1];
                o[t][2] += t2[2]; o[t][3] += t2[3];
            }
            f32x4 rt = rv[wq * 64 + lane];
            rs[0] += rt[0]; rs[1] += rt[1]; rs[2] += rt[2]; rs[3] += rt[3];

            float inv[4];
#pragma unroll
            for (int r = 0; r < 4; ++r) inv[r] = 1.0f / rsum16(rs[r]);
#pragma unroll
            for (int t = 0; t < 8; ++t)
#pragma unroll
                for (int r = 0; r < 4; ++r) {
                    int s = q0 + wq * 16 + qd * 4 + r;
                    out[((bS + s) * H_ + h) * 128 + t * 16 + l16] =
                        f2bf(o[t][r] * inv[r]);
                }
        }
        __syncthreads();              // scratch reads done before next stage
    }
}

// ---------------------------------------------------------------------------
extern "C" void kernel_launch(void* const* d_in, const int* in_sizes, int n_in,
                              void* d_out, int out_size, void* d_ws, size_t ws_size,
                              hipStream_t stream)
{
    const float* hs  = (const float*)d_in[0];
    const int*   pos = (const int*)d_in[1];
    const float* Wq  = (const float*)d_in[2];
    const float* Wk  = (const float*)d_in[3];
    const float* Wv  = (const float*)d_in[4];
    const float* Wo  = (const float*)d_in[5];
    const float* qnw = (const float*)d_in[6];
    const float* knw = (const float*)d_in[7];
    float* out = (float*)d_out;
    short* ws  = (short*)d_ws;

    short* hsb   = ws;                         // 4096 x 2048
    short* Wqkvb = hsb + (long)M_ * D_;        // 2432 x 2048 (Wq|Wk|Wv rows)
    short* Wob   = Wqkvb + (long)2432 * D_;    // 2048 x 2048
    short* qk_ws = Wob + (long)D_ * 2048;      // 4096 x 1920 (q | k fused)
    short* vt_ws = qk_ws + (long)M_ * NQK_;    // 512 x 4096  (V^T)
    short* ao_ws = vt_ws + (long)512 * M_;     // 4096 x 2048

    cvt_all<<<17152, 256, 0, stream>>>(hs, Wq, Wk, Wv, Wo, ws);

    gemm_bt<3><<<dim3(32, 38), 256, 0, stream>>>(
        hsb, Wqkvb, qk_ws, vt_ws, M_, 2432, D_);

    rms_rope<<<(65536 + 16384) / 4, 256, 0, stream>>>(qk_ws, qnw, knw, pos);

    attn<<<dim3(16, 32), 512, 0, stream>>>(qk_ws, vt_ws, ao_ws);

    gemm_bt<2><<<dim3(32, 32), 256, 0, stream>>>(
        ao_ws, Wob, (void*)out, nullptr, M_, D_, H_ * VD_);
}